// Round 8
// baseline (154.821 us; speedup 1.0000x reference)
//
#include <hip/hip_runtime.h>
#include <hip/hip_bf16.h>

// MultiheadAttention: out = (softmax_causal((Xq Wq^T)(Xk Wk^T)^T / 8) (Xv Wv^T)) Wo^T
// B=2 S=2048 D=1024 H=16 dk=64. bf16 MFMA (16x16x32), fp32 accum.
// R8: flash = KV-split (one q-tile/block, 8 waves in 2 groups over disjoint
//     KV halves, own dbuf K/V per group, end-of-block merge via LDS).
//     cvt/proj_qkv(8-phase)/proj_out unchanged from R7.

typedef __attribute__((ext_vector_type(8))) __bf16 bf16x8;
typedef __attribute__((ext_vector_type(4))) __bf16 bf16x4;
typedef __attribute__((ext_vector_type(4))) float f32x4;

#define MFMA16(a, b, c) __builtin_amdgcn_mfma_f32_16x16x32_bf16((a), (b), (c), 0, 0, 0)

constexpr int D_MODEL = 1024;
constexpr int HEADS   = 16;
constexpr int DKH     = 64;
constexpr int BATCH   = 2;
constexpr int SEQ     = 2048;
constexpr int M_ROWS  = BATCH * SEQ;  // 4096
constexpr int QB = 64, KB = 64, NT = SEQ / QB;  // 32 q-tiles

typedef const unsigned int __attribute__((address_space(1)))* gas_u32;
typedef unsigned int __attribute__((address_space(3)))* las_u32;

// ---------------------------------------------------------------------------
// fp32 -> bf16 convert; seg 3 (Wq) pre-scaled by 1/8.
// Segs 0-5 granule-swizzled for the 8-phase GEMM staging (rule #21).
// ---------------------------------------------------------------------------
struct CvtArgs {
  const float* src[7];
  __bf16* dst[7];
  int n8[7];
};

__global__ __launch_bounds__(256) void cvt_bf16(CvtArgs a) {
  const int z = blockIdx.z;
  const int i = blockIdx.x * 256 + threadIdx.x;
  if (i >= a.n8[z]) return;
  const float sc = (z == 3) ? 0.125f : 1.0f;
  const float4* s = (const float4*)a.src[z] + (size_t)i * 2;
  float4 x = s[0], y = s[1];
  bf16x8 o = {(__bf16)(x.x * sc), (__bf16)(x.y * sc), (__bf16)(x.z * sc), (__bf16)(x.w * sc),
              (__bf16)(y.x * sc), (__bf16)(y.y * sc), (__bf16)(y.z * sc), (__bf16)(y.w * sc)};
  size_t oi = (size_t)i;
  if (z < 6) {
    const int row = i >> 7;  // 1024 elems = 128 granules per row
    oi = (size_t)((i & ~7) | ((i & 7) ^ (row & 7)));
  }
  *(bf16x8*)(a.dst[z] + oi * 8) = o;
}

// ---------------------------------------------------------------------------
// 8-phase 256x256 GEMM (unchanged from R7)
// ---------------------------------------------------------------------------
__global__ __launch_bounds__(512, 2) void proj_qkv(
    const __bf16* __restrict__ Xq, const __bf16* __restrict__ Xk,
    const __bf16* __restrict__ Xv, const __bf16* __restrict__ Wq,
    const __bf16* __restrict__ Wk, const __bf16* __restrict__ Wv,
    __bf16* __restrict__ Q, __bf16* __restrict__ K, __bf16* __restrict__ Vt) {
  __shared__ alignas(16) __bf16 As[2 * 256 * 64];  // 64 KB
  __shared__ alignas(16) __bf16 Bs[2 * 256 * 64];  // 64 KB

  int f = (blockIdx.z * gridDim.y + blockIdx.y) * gridDim.x + blockIdx.x;
  f = (f & 7) * 24 + (f >> 3);
  const int bx = f & 3, by = (f >> 2) & 15, bz = f >> 6;

  const __bf16* Ag; const __bf16* Bg;
  if (bz == 0)      { Ag = Xq; Bg = Wq; }
  else if (bz == 1) { Ag = Xk; Bg = Wk; }
  else              { Ag = Xv; Bg = Wv; }

  const int bm = by * 256, bn = bx * 256;
  const int tid = threadIdx.x, ln = tid & 63, wv = tid >> 6;
  const int wr = wv >> 2, wc = wv & 3;
  const int fr = ln & 15, fg = ln >> 4;

  auto stageA = [&](int buf, int h, int t) {
    const int kt = t * 64;
#pragma unroll
    for (int l = 0; l < 2; ++l) {
      const int gbase = l * 512 + wv * 64;
      const int d = gbase + ln;
      const __bf16* src = Ag + (size_t)(bm + h * 128 + (d >> 3)) * 1024 + kt + (d & 7) * 8;
      __builtin_amdgcn_global_load_lds((gas_u32)src,
          (las_u32)(As + (size_t)(buf * 2048 + h * 1024 + gbase) * 8), 16, 0, 0);
    }
  };
  auto stageB = [&](int buf, int h, int t) {
    const int kt = t * 64;
#pragma unroll
    for (int l = 0; l < 2; ++l) {
      const int gbase = l * 512 + wv * 64;
      const int d = gbase + ln;
      const __bf16* src = Bg + (size_t)(bn + h * 128 + (d >> 3)) * 1024 + kt + (d & 7) * 8;
      __builtin_amdgcn_global_load_lds((gas_u32)src,
          (las_u32)(Bs + (size_t)(buf * 2048 + h * 1024 + gbase) * 8), 16, 0, 0);
    }
  };

  f32x4 acc[8][4];
#pragma unroll
  for (int m = 0; m < 8; ++m)
#pragma unroll
    for (int n = 0; n < 4; ++n) acc[m][n] = (f32x4){0.f, 0.f, 0.f, 0.f};

  bf16x8 ra[4][2], rb[4][2];

  auto loadA = [&](int buf, int mbase) {
#pragma unroll
    for (int m = 0; m < 4; ++m)
#pragma unroll
      for (int kk = 0; kk < 2; ++kk) {
        const int row = wr * 128 + (mbase + m) * 16 + fr;
        ra[m][kk] = *(const bf16x8*)&As[(buf * 256 + row) * 64 +
                                        (((kk * 4 + fg) ^ (row & 7)) << 3)];
      }
  };
  auto loadB = [&](int buf, int n0) {
#pragma unroll
    for (int n = 0; n < 2; ++n)
#pragma unroll
      for (int kk = 0; kk < 2; ++kk) {
        const int row = wc * 64 + (n0 + n) * 16 + fr;
        rb[n0 + n][kk] = *(const bf16x8*)&Bs[(buf * 256 + row) * 64 +
                                             (((kk * 4 + fg) ^ (row & 7)) << 3)];
      }
  };
  auto quad = [&](int mb, int nb) {
    __builtin_amdgcn_s_setprio(1);
#pragma unroll
    for (int m = 0; m < 4; ++m)
#pragma unroll
      for (int n = 0; n < 2; ++n) {
        acc[mb + m][nb + n] = MFMA16(ra[m][0], rb[nb + n][0], acc[mb + m][nb + n]);
        acc[mb + m][nb + n] = MFMA16(ra[m][1], rb[nb + n][1], acc[mb + m][nb + n]);
      }
    __builtin_amdgcn_s_setprio(0);
  };

  stageB(0, 0, 0); stageB(0, 1, 0); stageA(0, 0, 0); stageA(0, 1, 0);
  stageB(1, 0, 1); stageA(1, 0, 1);
  asm volatile("s_waitcnt vmcnt(4)" ::: "memory");
  __builtin_amdgcn_s_barrier();

#pragma unroll 1
  for (int it = 0; it < 8; ++it) {
    const int T0 = 2 * it, T1 = 2 * it + 1;
    const bool nl = (it < 7);

    loadA(0, 0); loadB(0, 0);
    stageB(1, 1, T1);
    __builtin_amdgcn_s_barrier();
    quad(0, 0);
    __builtin_amdgcn_s_barrier();

    loadB(0, 2);
    stageA(1, 1, T1);
    __builtin_amdgcn_s_barrier();
    quad(0, 2);
    __builtin_amdgcn_s_barrier();

    loadA(0, 4);
    if (nl) stageB(0, 0, T0 + 2);
    __builtin_amdgcn_s_barrier();
    quad(4, 0);
    __builtin_amdgcn_s_barrier();

    if (nl) {
      stageB(0, 1, T0 + 2);
      asm volatile("s_waitcnt vmcnt(4)" ::: "memory");
    } else {
      asm volatile("s_waitcnt vmcnt(0)" ::: "memory");
    }
    __builtin_amdgcn_s_barrier();
    quad(4, 2);
    __builtin_amdgcn_s_barrier();

    loadA(1, 0); loadB(1, 0);
    if (nl) stageA(0, 0, T0 + 2);
    __builtin_amdgcn_s_barrier();
    quad(0, 0);
    __builtin_amdgcn_s_barrier();

    loadB(1, 2);
    if (nl) stageA(0, 1, T0 + 2);
    __builtin_amdgcn_s_barrier();
    quad(0, 2);
    __builtin_amdgcn_s_barrier();

    loadA(1, 4);
    if (nl) stageB(1, 0, T1 + 2);
    __builtin_amdgcn_s_barrier();
    quad(4, 0);
    __builtin_amdgcn_s_barrier();

    if (nl) {
      stageA(1, 0, T1 + 2);
      asm volatile("s_waitcnt vmcnt(4)" ::: "memory");
    }
    __builtin_amdgcn_s_barrier();
    quad(4, 2);
    __builtin_amdgcn_s_barrier();
  }

  if (bz == 2) {
    const int b = bm >> 11;
#pragma unroll
    for (int m = 0; m < 8; ++m)
#pragma unroll
      for (int n = 0; n < 4; ++n) {
        const int col = bn + wc * 64 + n * 16 + fr;
        const int s0  = (bm + wr * 128 + m * 16 + fg * 4) & (SEQ - 1);
        bf16x4 o = {(__bf16)acc[m][n][0], (__bf16)acc[m][n][1],
                    (__bf16)acc[m][n][2], (__bf16)acc[m][n][3]};
        *(bf16x4*)(Vt + (((size_t)(b * 1024 + col)) << 11) + s0) = o;
      }
  } else {
    __bf16* C = (bz == 0) ? Q : K;
#pragma unroll
    for (int m = 0; m < 8; ++m)
#pragma unroll
      for (int n = 0; n < 4; ++n)
#pragma unroll
        for (int r = 0; r < 4; ++r) {
          const int row = bm + wr * 128 + m * 16 + fg * 4 + r;
          const int col = bn + wc * 64 + n * 16 + fr;
          C[(size_t)row * 1024 + col] = (__bf16)acc[m][n][r];
        }
  }
}

// ---------------------------------------------------------------------------
// m97-style 128^2 GEMM (unchanged; A and Wo LINEAR layouts)
// ---------------------------------------------------------------------------
__global__ __launch_bounds__(256) void proj_out(const __bf16* __restrict__ Aattn,
                                                const __bf16* __restrict__ Wo,
                                                float* __restrict__ Out) {
  __shared__ alignas(16) __bf16 As[128 * 64];
  __shared__ alignas(16) __bf16 Bs[128 * 64];

  const int tid = threadIdx.x, ln = tid & 63, wv = tid >> 6;
  const int wr = wv >> 1, wc = wv & 1;
  const int fr = ln & 15, fg = ln >> 4;
  const int bm = blockIdx.y * 128, bn = blockIdx.x * 128;

  f32x4 acc[4][4];
#pragma unroll
  for (int m = 0; m < 4; ++m)
#pragma unroll
    for (int n = 0; n < 4; ++n) acc[m][n] = (f32x4){0.f, 0.f, 0.f, 0.f};

  for (int kt = 0; kt < 1024; kt += 64) {
    __syncthreads();
#pragma unroll
    for (int i = 0; i < 4; ++i) {
      const int c = wv * 4 + i;
      const int byte = c * 1024 + ln * 16;
      const int row = byte >> 7;
      const int col = (byte & 127) >> 1;
      const __bf16* ga = Aattn + (size_t)(bm + row) * 1024 + kt + col;
      const __bf16* gb = Wo + (size_t)(bn + row) * 1024 + kt + col;
      __builtin_amdgcn_global_load_lds((gas_u32)ga, (las_u32)(As + c * 512), 16, 0, 0);
      __builtin_amdgcn_global_load_lds((gas_u32)gb, (las_u32)(Bs + c * 512), 16, 0, 0);
    }
    __syncthreads();

#pragma unroll
    for (int kk = 0; kk < 2; ++kk) {
      const int kc = kk * 32 + fg * 8;
      bf16x8 af[4], bfv[4];
#pragma unroll
      for (int m = 0; m < 4; ++m)
        af[m] = *(const bf16x8*)&As[(wr * 64 + m * 16 + fr) * 64 + kc];
#pragma unroll
      for (int n = 0; n < 4; ++n)
        bfv[n] = *(const bf16x8*)&Bs[(wc * 64 + n * 16 + fr) * 64 + kc];
#pragma unroll
      for (int m = 0; m < 4; ++m)
#pragma unroll
        for (int n = 0; n < 4; ++n) acc[m][n] = MFMA16(af[m], bfv[n], acc[m][n]);
    }
  }

#pragma unroll
  for (int m = 0; m < 4; ++m)
#pragma unroll
    for (int n = 0; n < 4; ++n)
#pragma unroll
      for (int r = 0; r < 4; ++r) {
        const int row = bm + wr * 64 + m * 16 + fg * 4 + r;
        const int col = bn + wc * 64 + n * 16 + fr;
        Out[(size_t)row * 1024 + col] = acc[m][n][r];
      }
}

// ---------------------------------------------------------------------------
// Flash attention, causal, KV-split. Block = ONE q-tile (64 rows), 8 waves in
// 2 groups of 4. Group 0: KV tiles [0,h0); group 1: [h0,len), len=qt+1,
// h0=ceil(len/2). Each group: own dbuf K/V LDS, independent online softmax
// (defer-max THR=8, ones-MFMA row sums). End-of-block merge via LDS.
// ---------------------------------------------------------------------------
__device__ __forceinline__ int SWZ(int row, int col) {
  return row * 64 + (col ^ ((row & 7) << 3));
}

struct TileState {
  f32x4 acc[4];
  f32x4 l4;
  float m_r[4];
  bf16x8 q0, q1;
};

__global__ __launch_bounds__(512, 4) void flash_attn(
    const __bf16* __restrict__ Q, const __bf16* __restrict__ K,
    const __bf16* __restrict__ Vt, __bf16* __restrict__ O) {
  __shared__ alignas(16) __bf16 Ks[2][2][64 * 64];  // [group][buf] 32 KB
  __shared__ alignas(16) __bf16 Vs[2][2][64 * 64];  // 32 KB
  __shared__ alignas(16) __bf16 Ps[8][16 * 64];     // 16 KB (reused for merge)

  const int qt = NT - 1 - blockIdx.x;   // long blocks launch first
  const int b  = blockIdx.y >> 4;
  const int h  = blockIdx.y & 15;
  const int tid  = threadIdx.x;
  const int lane = tid & 63, wave = tid >> 6;
  const int grp = wave >> 2, w4 = wave & 3;
  const int fr = lane & 15, fg = lane >> 4;
  const int gtid = tid & 255;
  const int sr = gtid >> 2;          // staging row (k for K, dk for V^T)
  const int sc = (gtid & 3) * 16;    // staging col chunk

  const int len = qt + 1;
  const int h0  = (len + 1) >> 1;    // group0 tiles [0,h0), group1 [h0,len)
  const int t0  = grp ? h0 : 0;

  const __bf16* Kbase = K + (size_t)b * SEQ * D_MODEL + h * DKH;
  const __bf16* Vbase = Vt + (size_t)(blockIdx.y * DKH + sr) * SEQ;

  TileState S;
  {
    const size_t qrow = (size_t)(b * SEQ + qt * QB + w4 * 16 + fr) * D_MODEL + h * DKH;
    S.q0 = *(const bf16x8*)(Q + qrow + fg * 8);
    S.q1 = *(const bf16x8*)(Q + qrow + 32 + fg * 8);
  }
#pragma unroll
  for (int n = 0; n < 4; ++n) S.acc[n] = (f32x4){0.f, 0.f, 0.f, 0.f};
  S.l4 = (f32x4){0.f, 0.f, 0.f, 0.f};
#pragma unroll
  for (int r = 0; r < 4; ++r) S.m_r[r] = -INFINITY;

  const bf16x8 ones = {(__bf16)1.f, (__bf16)1.f, (__bf16)1.f, (__bf16)1.f,
                       (__bf16)1.f, (__bf16)1.f, (__bf16)1.f, (__bf16)1.f};

  // prologue: stage this group's first tile into its buf 0 (t0 is always a
  // valid tile index <= 16 even if the group range is empty -> in-bounds)
  {
    const __bf16* kp = Kbase + (size_t)(t0 * KB + sr) * D_MODEL + sc;
    bf16x8 k0 = *(const bf16x8*)kp;
    bf16x8 k1 = *(const bf16x8*)(kp + 8);
    const __bf16* vp = Vbase + t0 * KB + sc;
    bf16x8 v0 = *(const bf16x8*)vp;
    bf16x8 v1 = *(const bf16x8*)(vp + 8);
    *(bf16x8*)&Ks[grp][0][SWZ(sr, sc)]     = k0;
    *(bf16x8*)&Ks[grp][0][SWZ(sr, sc + 8)] = k1;
    *(bf16x8*)&Vs[grp][0][SWZ(sr, sc)]     = v0;
    *(bf16x8*)&Vs[grp][0][SWZ(sr, sc + 8)] = v1;
  }
  __syncthreads();

  auto step = [&](const int t, const __bf16* __restrict__ Kt,
                  const __bf16* __restrict__ Vtl, __bf16* __restrict__ ps) {
    f32x4 s[4];
    __builtin_amdgcn_s_setprio(1);
#pragma unroll
    for (int kb = 0; kb < 4; ++kb) {
      f32x4 a = (f32x4){0.f, 0.f, 0.f, 0.f};
      bf16x8 kf0 = *(const bf16x8*)&Kt[SWZ(kb * 16 + fr, fg * 8)];
      bf16x8 kf1 = *(const bf16x8*)&Kt[SWZ(kb * 16 + fr, 32 + fg * 8)];
      a = MFMA16(S.q0, kf0, a);
      a = MFMA16(S.q1, kf1, a);
      s[kb] = a;
    }
    __builtin_amdgcn_s_setprio(0);

    if (t == qt) {  // causal mask: diagonal tile only
      const int q0r = qt * QB + w4 * 16 + fg * 4;
      const int kc0 = t * KB + fr;
#pragma unroll
      for (int kb = 0; kb < 4; ++kb)
#pragma unroll
        for (int r = 0; r < 4; ++r)
          if (kc0 + kb * 16 > q0r + r) s[kb][r] = -INFINITY;
    }

    float tmax[4];
#pragma unroll
    for (int r = 0; r < 4; ++r)
      tmax[r] = fmaxf(fmaxf(s[0][r], s[1][r]), fmaxf(s[2][r], s[3][r]));

    bool need = false;
#pragma unroll
    for (int r = 0; r < 4; ++r) need |= (tmax[r] > S.m_r[r] + 8.f);
    if (__any(need)) {
#pragma unroll
      for (int off = 1; off < 16; off <<= 1)
#pragma unroll
        for (int r = 0; r < 4; ++r) tmax[r] = fmaxf(tmax[r], __shfl_xor(tmax[r], off));
      float corr[4];
#pragma unroll
      for (int r = 0; r < 4; ++r) {
        const float mn = fmaxf(S.m_r[r], tmax[r]);
        corr[r] = __expf(S.m_r[r] - mn);
        S.m_r[r] = mn;
      }
#pragma unroll
      for (int n = 0; n < 4; ++n)
#pragma unroll
        for (int r = 0; r < 4; ++r) S.acc[n][r] *= corr[r];
#pragma unroll
      for (int r = 0; r < 4; ++r) S.l4[r] *= corr[r];
    }

#pragma unroll
    for (int kb = 0; kb < 4; ++kb)
#pragma unroll
      for (int r = 0; r < 4; ++r) {
        const float p = __expf(s[kb][r] - S.m_r[r]);
        ps[SWZ(fg * 4 + r, kb * 16 + fr)] = (__bf16)p;
      }

    __builtin_amdgcn_s_setprio(1);
#pragma unroll
    for (int k2 = 0; k2 < 2; ++k2) {
      bf16x8 pf = *(const bf16x8*)&ps[SWZ(fr, k2 * 32 + fg * 8)];
#pragma unroll
      for (int n = 0; n < 4; ++n) {
        bf16x8 vf = *(const bf16x8*)&Vtl[SWZ(n * 16 + fr, k2 * 32 + fg * 8)];
        S.acc[n] = MFMA16(pf, vf, S.acc[n]);
      }
      S.l4 = MFMA16(pf, ones, S.l4);
    }
    __builtin_amdgcn_s_setprio(0);
  };

#pragma unroll 1
  for (int i = 0; i < h0; ++i) {
    const int t = t0 + i;
    const int cur = i & 1;
    const bool active = (t < len);
    const bool pf = grp ? (t + 1 < len) : (t + 1 < h0);

    // issue next tile's global loads early (latency hides under compute)
    bf16x8 nk0, nk1, nv0, nv1;
    if (pf) {
      const __bf16* kp = Kbase + (size_t)((t + 1) * KB + sr) * D_MODEL + sc;
      nk0 = *(const bf16x8*)kp;
      nk1 = *(const bf16x8*)(kp + 8);
      const __bf16* vp = Vbase + (t + 1) * KB + sc;
      nv0 = *(const bf16x8*)vp;
      nv1 = *(const bf16x8*)(vp + 8);
    }

    if (active) step(t, &Ks[grp][cur][0], &Vs[grp][cur][0], &Ps[wave][0]);

    if (pf) {
      *(bf16x8*)&Ks[grp][cur ^ 1][SWZ(sr, sc)]     = nk0;
      *(bf16x8*)&Ks[grp][cur ^ 1][SWZ(sr, sc + 8)] = nk1;
      *(bf16x8*)&Vs[grp][cur ^ 1][SWZ(sr, sc)]     = nv0;
      *(bf16x8*)&Vs[grp][cur ^ 1][SWZ(sr, sc + 8)] = nv1;
    }
    __syncthreads();
  }

  // ---- merge group1 into group0 (Ks/Ps reused; all tile reads are done) ----
  float* accb = (float*)&Ps[0][0];       // 4 waves x 16x64 f32 = 16 KB
  float* mb   = (float*)&Ks[0][0][0];    // 64 floats
  float* lb   = mb + 64;
  if (grp == 1) {
#pragma unroll
    for (int n = 0; n < 4; ++n)
#pragma unroll
      for (int r = 0; r < 4; ++r)
        accb[w4 * 1024 + (fg * 4 + r) * 64 + n * 16 + fr] = S.acc[n][r];
    if (fr == 0) {
#pragma unroll
      for (int r = 0; r < 4; ++r) {
        mb[w4 * 16 + fg * 4 + r] = S.m_r[r];
        lb[w4 * 16 + fg * 4 + r] = S.l4[r];
      }
    }
  }
  __syncthreads();
  if (grp == 0) {
    float w0[4], w1[4], li[4];
#pragma unroll
    for (int r = 0; r < 4; ++r) {
      const float pm = mb[w4 * 16 + fg * 4 + r];
      const float pl = lb[w4 * 16 + fg * 4 + r];
      const float ms = fmaxf(S.m_r[r], pm);
      w0[r] = __expf(S.m_r[r] - ms);
      w1[r] = __expf(pm - ms);
      li[r] = 1.f / (S.l4[r] * w0[r] + pl * w1[r]);
    }
    const size_t obase = (size_t)(b * SEQ + qt * QB + w4 * 16) * D_MODEL + h * DKH;
#pragma unroll
    for (int n = 0; n < 4; ++n)
#pragma unroll
      for (int r = 0; r < 4; ++r) {
        const int row = fg * 4 + r;
        const float o = (S.acc[n][r] * w0[r] +
                         accb[w4 * 1024 + row * 64 + n * 16 + fr] * w1[r]) * li[r];
        O[obase + (size_t)row * D_MODEL + n * 16 + fr] = (__bf16)o;
      }
  }
}

// ---------------------------------------------------------------------------
extern "C" void kernel_launch(void* const* d_in, const int* in_sizes, int n_in,
                              void* d_out, int out_size, void* d_ws, size_t ws_size,
                              hipStream_t stream) {
  const float* q_src = (const float*)d_in[0];
  const float* k_src = (const float*)d_in[1];
  const float* v_src = (const float*)d_in[2];
  // d_in[3] = causal tril mask (fixed) -> applied analytically
  const float* Wq = (const float*)d_in[4];
  const float* Wk = (const float*)d_in[5];
  const float* Wv = (const float*)d_in[6];
  const float* Wo = (const float*)d_in[7];

  const size_t NE = (size_t)M_ROWS * D_MODEL;  // 4M elems
  const size_t NW = (size_t)D_MODEL * D_MODEL; // 1M elems
  __bf16* Xq  = (__bf16*)d_ws;
  __bf16* Xk  = Xq + NE;
  __bf16* Xv  = Xk + NE;
  __bf16* Wqb = Xv + NE;
  __bf16* Wkb = Wqb + NW;
  __bf16* Wvb = Wkb + NW;
  __bf16* Wob = Wvb + NW;
  __bf16* Q   = Wob + NW;
  __bf16* K   = Q + NE;
  __bf16* Vt  = K + NE;
  __bf16* A   = Xq;  // Xq consumed by proj_qkv before flash writes A

  CvtArgs ca;
  ca.src[0] = q_src; ca.dst[0] = Xq;  ca.n8[0] = (int)(NE / 8);
  ca.src[1] = k_src; ca.dst[1] = Xk;  ca.n8[1] = (int)(NE / 8);
  ca.src[2] = v_src; ca.dst[2] = Xv;  ca.n8[2] = (int)(NE / 8);
  ca.src[3] = Wq;    ca.dst[3] = Wqb; ca.n8[3] = (int)(NW / 8);  // x1/8
  ca.src[4] = Wk;    ca.dst[4] = Wkb; ca.n8[4] = (int)(NW / 8);
  ca.src[5] = Wv;    ca.dst[5] = Wvb; ca.n8[5] = (int)(NW / 8);
  ca.src[6] = Wo;    ca.dst[6] = Wob; ca.n8[6] = (int)(NW / 8);

  cvt_bf16<<<dim3((unsigned)(NE / 8 / 256), 1, 7), dim3(256), 0, stream>>>(ca);
  proj_qkv<<<dim3(4, 16, 3), dim3(512), 0, stream>>>(
      Xq, Xk, Xv, Wqb, Wkb, Wvb, Q, K, Vt);
  flash_attn<<<dim3(NT, BATCH * HEADS), dim3(512), 0, stream>>>(Q, K, Vt, A);
  proj_out<<<dim3(D_MODEL / 128, M_ROWS / 128), dim3(256), 0, stream>>>(
      A, Wob, (float*)d_out);
}

// Round 9
// 153.557 us; speedup vs baseline: 1.0082x; 1.0082x over previous
//
#include <hip/hip_runtime.h>
#include <hip/hip_bf16.h>

// MultiheadAttention: out = (softmax_causal((Xq Wq^T)(Xk Wk^T)^T / 8) (Xv Wv^T)) Wo^T
// B=2 S=2048 D=1024 H=16 dk=64. bf16 MFMA (16x16x32), fp32 accum.
// R9: R8 KV-split flash with launch_bounds(512,2) — R8's (512,4) capped VGPR
//     at 60, sinking the K/V prefetch to just-before-use (serial iters).
//     LDS (80KB) already pins occupancy at 2 blocks/CU, so nothing is lost.
//     cvt/proj_qkv(8-phase)/proj_out unchanged.

typedef __attribute__((ext_vector_type(8))) __bf16 bf16x8;
typedef __attribute__((ext_vector_type(4))) __bf16 bf16x4;
typedef __attribute__((ext_vector_type(4))) float f32x4;

#define MFMA16(a, b, c) __builtin_amdgcn_mfma_f32_16x16x32_bf16((a), (b), (c), 0, 0, 0)

constexpr int D_MODEL = 1024;
constexpr int HEADS   = 16;
constexpr int DKH     = 64;
constexpr int BATCH   = 2;
constexpr int SEQ     = 2048;
constexpr int M_ROWS  = BATCH * SEQ;  // 4096
constexpr int QB = 64, KB = 64, NT = SEQ / QB;  // 32 q-tiles

typedef const unsigned int __attribute__((address_space(1)))* gas_u32;
typedef unsigned int __attribute__((address_space(3)))* las_u32;

// ---------------------------------------------------------------------------
// fp32 -> bf16 convert; seg 3 (Wq) pre-scaled by 1/8.
// Segs 0-5 granule-swizzled for the 8-phase GEMM staging (rule #21).
// ---------------------------------------------------------------------------
struct CvtArgs {
  const float* src[7];
  __bf16* dst[7];
  int n8[7];
};

__global__ __launch_bounds__(256) void cvt_bf16(CvtArgs a) {
  const int z = blockIdx.z;
  const int i = blockIdx.x * 256 + threadIdx.x;
  if (i >= a.n8[z]) return;
  const float sc = (z == 3) ? 0.125f : 1.0f;
  const float4* s = (const float4*)a.src[z] + (size_t)i * 2;
  float4 x = s[0], y = s[1];
  bf16x8 o = {(__bf16)(x.x * sc), (__bf16)(x.y * sc), (__bf16)(x.z * sc), (__bf16)(x.w * sc),
              (__bf16)(y.x * sc), (__bf16)(y.y * sc), (__bf16)(y.z * sc), (__bf16)(y.w * sc)};
  size_t oi = (size_t)i;
  if (z < 6) {
    const int row = i >> 7;  // 1024 elems = 128 granules per row
    oi = (size_t)((i & ~7) | ((i & 7) ^ (row & 7)));
  }
  *(bf16x8*)(a.dst[z] + oi * 8) = o;
}

// ---------------------------------------------------------------------------
// 8-phase 256x256 GEMM (unchanged from R7)
// ---------------------------------------------------------------------------
__global__ __launch_bounds__(512, 2) void proj_qkv(
    const __bf16* __restrict__ Xq, const __bf16* __restrict__ Xk,
    const __bf16* __restrict__ Xv, const __bf16* __restrict__ Wq,
    const __bf16* __restrict__ Wk, const __bf16* __restrict__ Wv,
    __bf16* __restrict__ Q, __bf16* __restrict__ K, __bf16* __restrict__ Vt) {
  __shared__ alignas(16) __bf16 As[2 * 256 * 64];  // 64 KB
  __shared__ alignas(16) __bf16 Bs[2 * 256 * 64];  // 64 KB

  int f = (blockIdx.z * gridDim.y + blockIdx.y) * gridDim.x + blockIdx.x;
  f = (f & 7) * 24 + (f >> 3);
  const int bx = f & 3, by = (f >> 2) & 15, bz = f >> 6;

  const __bf16* Ag; const __bf16* Bg;
  if (bz == 0)      { Ag = Xq; Bg = Wq; }
  else if (bz == 1) { Ag = Xk; Bg = Wk; }
  else              { Ag = Xv; Bg = Wv; }

  const int bm = by * 256, bn = bx * 256;
  const int tid = threadIdx.x, ln = tid & 63, wv = tid >> 6;
  const int wr = wv >> 2, wc = wv & 3;
  const int fr = ln & 15, fg = ln >> 4;

  auto stageA = [&](int buf, int h, int t) {
    const int kt = t * 64;
#pragma unroll
    for (int l = 0; l < 2; ++l) {
      const int gbase = l * 512 + wv * 64;
      const int d = gbase + ln;
      const __bf16* src = Ag + (size_t)(bm + h * 128 + (d >> 3)) * 1024 + kt + (d & 7) * 8;
      __builtin_amdgcn_global_load_lds((gas_u32)src,
          (las_u32)(As + (size_t)(buf * 2048 + h * 1024 + gbase) * 8), 16, 0, 0);
    }
  };
  auto stageB = [&](int buf, int h, int t) {
    const int kt = t * 64;
#pragma unroll
    for (int l = 0; l < 2; ++l) {
      const int gbase = l * 512 + wv * 64;
      const int d = gbase + ln;
      const __bf16* src = Bg + (size_t)(bn + h * 128 + (d >> 3)) * 1024 + kt + (d & 7) * 8;
      __builtin_amdgcn_global_load_lds((gas_u32)src,
          (las_u32)(Bs + (size_t)(buf * 2048 + h * 1024 + gbase) * 8), 16, 0, 0);
    }
  };

  f32x4 acc[8][4];
#pragma unroll
  for (int m = 0; m < 8; ++m)
#pragma unroll
    for (int n = 0; n < 4; ++n) acc[m][n] = (f32x4){0.f, 0.f, 0.f, 0.f};

  bf16x8 ra[4][2], rb[4][2];

  auto loadA = [&](int buf, int mbase) {
#pragma unroll
    for (int m = 0; m < 4; ++m)
#pragma unroll
      for (int kk = 0; kk < 2; ++kk) {
        const int row = wr * 128 + (mbase + m) * 16 + fr;
        ra[m][kk] = *(const bf16x8*)&As[(buf * 256 + row) * 64 +
                                        (((kk * 4 + fg) ^ (row & 7)) << 3)];
      }
  };
  auto loadB = [&](int buf, int n0) {
#pragma unroll
    for (int n = 0; n < 2; ++n)
#pragma unroll
      for (int kk = 0; kk < 2; ++kk) {
        const int row = wc * 64 + (n0 + n) * 16 + fr;
        rb[n0 + n][kk] = *(const bf16x8*)&Bs[(buf * 256 + row) * 64 +
                                             (((kk * 4 + fg) ^ (row & 7)) << 3)];
      }
  };
  auto quad = [&](int mb, int nb) {
    __builtin_amdgcn_s_setprio(1);
#pragma unroll
    for (int m = 0; m < 4; ++m)
#pragma unroll
      for (int n = 0; n < 2; ++n) {
        acc[mb + m][nb + n] = MFMA16(ra[m][0], rb[nb + n][0], acc[mb + m][nb + n]);
        acc[mb + m][nb + n] = MFMA16(ra[m][1], rb[nb + n][1], acc[mb + m][nb + n]);
      }
    __builtin_amdgcn_s_setprio(0);
  };

  stageB(0, 0, 0); stageB(0, 1, 0); stageA(0, 0, 0); stageA(0, 1, 0);
  stageB(1, 0, 1); stageA(1, 0, 1);
  asm volatile("s_waitcnt vmcnt(4)" ::: "memory");
  __builtin_amdgcn_s_barrier();

#pragma unroll 1
  for (int it = 0; it < 8; ++it) {
    const int T0 = 2 * it, T1 = 2 * it + 1;
    const bool nl = (it < 7);

    loadA(0, 0); loadB(0, 0);
    stageB(1, 1, T1);
    __builtin_amdgcn_s_barrier();
    quad(0, 0);
    __builtin_amdgcn_s_barrier();

    loadB(0, 2);
    stageA(1, 1, T1);
    __builtin_amdgcn_s_barrier();
    quad(0, 2);
    __builtin_amdgcn_s_barrier();

    loadA(0, 4);
    if (nl) stageB(0, 0, T0 + 2);
    __builtin_amdgcn_s_barrier();
    quad(4, 0);
    __builtin_amdgcn_s_barrier();

    if (nl) {
      stageB(0, 1, T0 + 2);
      asm volatile("s_waitcnt vmcnt(4)" ::: "memory");
    } else {
      asm volatile("s_waitcnt vmcnt(0)" ::: "memory");
    }
    __builtin_amdgcn_s_barrier();
    quad(4, 2);
    __builtin_amdgcn_s_barrier();

    loadA(1, 0); loadB(1, 0);
    if (nl) stageA(0, 0, T0 + 2);
    __builtin_amdgcn_s_barrier();
    quad(0, 0);
    __builtin_amdgcn_s_barrier();

    loadB(1, 2);
    if (nl) stageA(0, 1, T0 + 2);
    __builtin_amdgcn_s_barrier();
    quad(0, 2);
    __builtin_amdgcn_s_barrier();

    loadA(1, 4);
    if (nl) stageB(1, 0, T1 + 2);
    __builtin_amdgcn_s_barrier();
    quad(4, 0);
    __builtin_amdgcn_s_barrier();

    if (nl) {
      stageA(1, 0, T1 + 2);
      asm volatile("s_waitcnt vmcnt(4)" ::: "memory");
    }
    __builtin_amdgcn_s_barrier();
    quad(4, 2);
    __builtin_amdgcn_s_barrier();
  }

  if (bz == 2) {
    const int b = bm >> 11;
#pragma unroll
    for (int m = 0; m < 8; ++m)
#pragma unroll
      for (int n = 0; n < 4; ++n) {
        const int col = bn + wc * 64 + n * 16 + fr;
        const int s0  = (bm + wr * 128 + m * 16 + fg * 4) & (SEQ - 1);
        bf16x4 o = {(__bf16)acc[m][n][0], (__bf16)acc[m][n][1],
                    (__bf16)acc[m][n][2], (__bf16)acc[m][n][3]};
        *(bf16x4*)(Vt + (((size_t)(b * 1024 + col)) << 11) + s0) = o;
      }
  } else {
    __bf16* C = (bz == 0) ? Q : K;
#pragma unroll
    for (int m = 0; m < 8; ++m)
#pragma unroll
      for (int n = 0; n < 4; ++n)
#pragma unroll
        for (int r = 0; r < 4; ++r) {
          const int row = bm + wr * 128 + m * 16 + fg * 4 + r;
          const int col = bn + wc * 64 + n * 16 + fr;
          C[(size_t)row * 1024 + col] = (__bf16)acc[m][n][r];
        }
  }
}

// ---------------------------------------------------------------------------
// m97-style 128^2 GEMM (unchanged; A and Wo LINEAR layouts). 256 blocks =
// full chip; 256^2 tile here would give only 64 blocks (25% fill) — worse.
// ---------------------------------------------------------------------------
__global__ __launch_bounds__(256) void proj_out(const __bf16* __restrict__ Aattn,
                                                const __bf16* __restrict__ Wo,
                                                float* __restrict__ Out) {
  __shared__ alignas(16) __bf16 As[128 * 64];
  __shared__ alignas(16) __bf16 Bs[128 * 64];

  const int tid = threadIdx.x, ln = tid & 63, wv = tid >> 6;
  const int wr = wv >> 1, wc = wv & 1;
  const int fr = ln & 15, fg = ln >> 4;
  const int bm = blockIdx.y * 128, bn = blockIdx.x * 128;

  f32x4 acc[4][4];
#pragma unroll
  for (int m = 0; m < 4; ++m)
#pragma unroll
    for (int n = 0; n < 4; ++n) acc[m][n] = (f32x4){0.f, 0.f, 0.f, 0.f};

  for (int kt = 0; kt < 1024; kt += 64) {
    __syncthreads();
#pragma unroll
    for (int i = 0; i < 4; ++i) {
      const int c = wv * 4 + i;
      const int byte = c * 1024 + ln * 16;
      const int row = byte >> 7;
      const int col = (byte & 127) >> 1;
      const __bf16* ga = Aattn + (size_t)(bm + row) * 1024 + kt + col;
      const __bf16* gb = Wo + (size_t)(bn + row) * 1024 + kt + col;
      __builtin_amdgcn_global_load_lds((gas_u32)ga, (las_u32)(As + c * 512), 16, 0, 0);
      __builtin_amdgcn_global_load_lds((gas_u32)gb, (las_u32)(Bs + c * 512), 16, 0, 0);
    }
    __syncthreads();

#pragma unroll
    for (int kk = 0; kk < 2; ++kk) {
      const int kc = kk * 32 + fg * 8;
      bf16x8 af[4], bfv[4];
#pragma unroll
      for (int m = 0; m < 4; ++m)
        af[m] = *(const bf16x8*)&As[(wr * 64 + m * 16 + fr) * 64 + kc];
#pragma unroll
      for (int n = 0; n < 4; ++n)
        bfv[n] = *(const bf16x8*)&Bs[(wc * 64 + n * 16 + fr) * 64 + kc];
#pragma unroll
      for (int m = 0; m < 4; ++m)
#pragma unroll
        for (int n = 0; n < 4; ++n) acc[m][n] = MFMA16(af[m], bfv[n], acc[m][n]);
    }
  }

#pragma unroll
  for (int m = 0; m < 4; ++m)
#pragma unroll
    for (int n = 0; n < 4; ++n)
#pragma unroll
      for (int r = 0; r < 4; ++r) {
        const int row = bm + wr * 64 + m * 16 + fg * 4 + r;
        const int col = bn + wc * 64 + n * 16 + fr;
        Out[(size_t)row * 1024 + col] = acc[m][n][r];
      }
}

// ---------------------------------------------------------------------------
// Flash attention, causal, KV-split (R8 structure). Block = ONE q-tile,
// 8 waves in 2 groups over disjoint KV halves, own dbuf K/V per group,
// end-of-block merge via LDS. launch_bounds(512,2): VGPR cap 256 so the
// K/V prefetch stays in registers across the compute phase (R8 lesson).
// ---------------------------------------------------------------------------
__device__ __forceinline__ int SWZ(int row, int col) {
  return row * 64 + (col ^ ((row & 7) << 3));
}

struct TileState {
  f32x4 acc[4];
  f32x4 l4;
  float m_r[4];
  bf16x8 q0, q1;
};

__global__ __launch_bounds__(512, 2) void flash_attn(
    const __bf16* __restrict__ Q, const __bf16* __restrict__ K,
    const __bf16* __restrict__ Vt, __bf16* __restrict__ O) {
  __shared__ alignas(16) __bf16 Ks[2][2][64 * 64];  // [group][buf] 32 KB
  __shared__ alignas(16) __bf16 Vs[2][2][64 * 64];  // 32 KB
  __shared__ alignas(16) __bf16 Ps[8][16 * 64];     // 16 KB (reused for merge)

  const int qt = NT - 1 - blockIdx.x;   // long blocks launch first
  const int b  = blockIdx.y >> 4;
  const int h  = blockIdx.y & 15;
  const int tid  = threadIdx.x;
  const int lane = tid & 63, wave = tid >> 6;
  const int grp = wave >> 2, w4 = wave & 3;
  const int fr = lane & 15, fg = lane >> 4;
  const int gtid = tid & 255;
  const int sr = gtid >> 2;          // staging row (k for K, dk for V^T)
  const int sc = (gtid & 3) * 16;    // staging col chunk

  const int len = qt + 1;
  const int h0  = (len + 1) >> 1;    // group0 tiles [0,h0), group1 [h0,len)
  const int t0  = grp ? h0 : 0;

  const __bf16* Kbase = K + (size_t)b * SEQ * D_MODEL + h * DKH;
  const __bf16* Vbase = Vt + (size_t)(blockIdx.y * DKH + sr) * SEQ;

  TileState S;
  {
    const size_t qrow = (size_t)(b * SEQ + qt * QB + w4 * 16 + fr) * D_MODEL + h * DKH;
    S.q0 = *(const bf16x8*)(Q + qrow + fg * 8);
    S.q1 = *(const bf16x8*)(Q + qrow + 32 + fg * 8);
  }
#pragma unroll
  for (int n = 0; n < 4; ++n) S.acc[n] = (f32x4){0.f, 0.f, 0.f, 0.f};
  S.l4 = (f32x4){0.f, 0.f, 0.f, 0.f};
#pragma unroll
  for (int r = 0; r < 4; ++r) S.m_r[r] = -INFINITY;

  const bf16x8 ones = {(__bf16)1.f, (__bf16)1.f, (__bf16)1.f, (__bf16)1.f,
                       (__bf16)1.f, (__bf16)1.f, (__bf16)1.f, (__bf16)1.f};

  // prologue: stage this group's first tile into its buf 0
  {
    const __bf16* kp = Kbase + (size_t)(t0 * KB + sr) * D_MODEL + sc;
    bf16x8 k0 = *(const bf16x8*)kp;
    bf16x8 k1 = *(const bf16x8*)(kp + 8);
    const __bf16* vp = Vbase + t0 * KB + sc;
    bf16x8 v0 = *(const bf16x8*)vp;
    bf16x8 v1 = *(const bf16x8*)(vp + 8);
    *(bf16x8*)&Ks[grp][0][SWZ(sr, sc)]     = k0;
    *(bf16x8*)&Ks[grp][0][SWZ(sr, sc + 8)] = k1;
    *(bf16x8*)&Vs[grp][0][SWZ(sr, sc)]     = v0;
    *(bf16x8*)&Vs[grp][0][SWZ(sr, sc + 8)] = v1;
  }
  __syncthreads();

  auto step = [&](const int t, const __bf16* __restrict__ Kt,
                  const __bf16* __restrict__ Vtl, __bf16* __restrict__ ps) {
    f32x4 s[4];
    __builtin_amdgcn_s_setprio(1);
#pragma unroll
    for (int kb = 0; kb < 4; ++kb) {
      f32x4 a = (f32x4){0.f, 0.f, 0.f, 0.f};
      bf16x8 kf0 = *(const bf16x8*)&Kt[SWZ(kb * 16 + fr, fg * 8)];
      bf16x8 kf1 = *(const bf16x8*)&Kt[SWZ(kb * 16 + fr, 32 + fg * 8)];
      a = MFMA16(S.q0, kf0, a);
      a = MFMA16(S.q1, kf1, a);
      s[kb] = a;
    }
    __builtin_amdgcn_s_setprio(0);

    if (t == qt) {  // causal mask: diagonal tile only
      const int q0r = qt * QB + w4 * 16 + fg * 4;
      const int kc0 = t * KB + fr;
#pragma unroll
      for (int kb = 0; kb < 4; ++kb)
#pragma unroll
        for (int r = 0; r < 4; ++r)
          if (kc0 + kb * 16 > q0r + r) s[kb][r] = -INFINITY;
    }

    float tmax[4];
#pragma unroll
    for (int r = 0; r < 4; ++r)
      tmax[r] = fmaxf(fmaxf(s[0][r], s[1][r]), fmaxf(s[2][r], s[3][r]));

    bool need = false;
#pragma unroll
    for (int r = 0; r < 4; ++r) need |= (tmax[r] > S.m_r[r] + 8.f);
    if (__any(need)) {
#pragma unroll
      for (int off = 1; off < 16; off <<= 1)
#pragma unroll
        for (int r = 0; r < 4; ++r) tmax[r] = fmaxf(tmax[r], __shfl_xor(tmax[r], off));
      float corr[4];
#pragma unroll
      for (int r = 0; r < 4; ++r) {
        const float mn = fmaxf(S.m_r[r], tmax[r]);
        corr[r] = __expf(S.m_r[r] - mn);
        S.m_r[r] = mn;
      }
#pragma unroll
      for (int n = 0; n < 4; ++n)
#pragma unroll
        for (int r = 0; r < 4; ++r) S.acc[n][r] *= corr[r];
#pragma unroll
      for (int r = 0; r < 4; ++r) S.l4[r] *= corr[r];
    }

#pragma unroll
    for (int kb = 0; kb < 4; ++kb)
#pragma unroll
      for (int r = 0; r < 4; ++r) {
        const float p = __expf(s[kb][r] - S.m_r[r]);
        ps[SWZ(fg * 4 + r, kb * 16 + fr)] = (__bf16)p;
      }

    __builtin_amdgcn_s_setprio(1);
#pragma unroll
    for (int k2 = 0; k2 < 2; ++k2) {
      bf16x8 pf = *(const bf16x8*)&ps[SWZ(fr, k2 * 32 + fg * 8)];
#pragma unroll
      for (int n = 0; n < 4; ++n) {
        bf16x8 vf = *(const bf16x8*)&Vtl[SWZ(n * 16 + fr, k2 * 32 + fg * 8)];
        S.acc[n] = MFMA16(pf, vf, S.acc[n]);
      }
      S.l4 = MFMA16(pf, ones, S.l4);
    }
    __builtin_amdgcn_s_setprio(0);
  };

#pragma unroll 1
  for (int i = 0; i < h0; ++i) {
    const int t = t0 + i;
    const int cur = i & 1;
    const bool active = (t < len);
    const bool pf = grp ? (t + 1 < len) : (t + 1 < h0);

    // issue next tile's global loads early (latency hides under compute)
    bf16x8 nk0, nk1, nv0, nv1;
    if (pf) {
      const __bf16* kp = Kbase + (size_t)((t + 1) * KB + sr) * D_MODEL + sc;
      nk0 = *(const bf16x8*)kp;
      nk1 = *(const bf16x8*)(kp + 8);
      const __bf16* vp = Vbase + (t + 1) * KB + sc;
      nv0 = *(const bf16x8*)vp;
      nv1 = *(const bf16x8*)(vp + 8);
    }

    if (active) step(t, &Ks[grp][cur][0], &Vs[grp][cur][0], &Ps[wave][0]);

    if (pf) {
      *(bf16x8*)&Ks[grp][cur ^ 1][SWZ(sr, sc)]     = nk0;
      *(bf16x8*)&Ks[grp][cur ^ 1][SWZ(sr, sc + 8)] = nk1;
      *(bf16x8*)&Vs[grp][cur ^ 1][SWZ(sr, sc)]     = nv0;
      *(bf16x8*)&Vs[grp][cur ^ 1][SWZ(sr, sc + 8)] = nv1;
    }
    __syncthreads();
  }

  // ---- merge group1 into group0 (Ks/Ps reused; all tile reads are done) ----
  float* accb = (float*)&Ps[0][0];       // 4 waves x 16x64 f32 = 16 KB
  float* mb   = (float*)&Ks[0][0][0];    // 64 floats
  float* lb   = mb + 64;
  if (grp == 1) {
#pragma unroll
    for (int n = 0; n < 4; ++n)
#pragma unroll
      for (int r = 0; r < 4; ++r)
        accb[w4 * 1024 + (fg * 4 + r) * 64 + n * 16 + fr] = S.acc[n][r];
    if (fr == 0) {
#pragma unroll
      for (int r = 0; r < 4; ++r) {
        mb[w4 * 16 + fg * 4 + r] = S.m_r[r];
        lb[w4 * 16 + fg * 4 + r] = S.l4[r];
      }
    }
  }
  __syncthreads();
  if (grp == 0) {
    float w0[4], w1[4], li[4];
#pragma unroll
    for (int r = 0; r < 4; ++r) {
      const float pm = mb[w4 * 16 + fg * 4 + r];
      const float pl = lb[w4 * 16 + fg * 4 + r];
      const float ms = fmaxf(S.m_r[r], pm);
      w0[r] = __expf(S.m_r[r] - ms);
      w1[r] = __expf(pm - ms);
      li[r] = 1.f / (S.l4[r] * w0[r] + pl * w1[r]);
    }
    const size_t obase = (size_t)(b * SEQ + qt * QB + w4 * 16) * D_MODEL + h * DKH;
#pragma unroll
    for (int n = 0; n < 4; ++n)
#pragma unroll
      for (int r = 0; r < 4; ++r) {
        const int row = fg * 4 + r;
        const float o = (S.acc[n][r] * w0[r] +
                         accb[w4 * 1024 + row * 64 + n * 16 + fr] * w1[r]) * li[r];
        O[obase + (size_t)row * D_MODEL + n * 16 + fr] = (__bf16)o;
      }
  }
}

// ---------------------------------------------------------------------------
extern "C" void kernel_launch(void* const* d_in, const int* in_sizes, int n_in,
                              void* d_out, int out_size, void* d_ws, size_t ws_size,
                              hipStream_t stream) {
  const float* q_src = (const float*)d_in[0];
  const float* k_src = (const float*)d_in[1];
  const float* v_src = (const float*)d_in[2];
  // d_in[3] = causal tril mask (fixed) -> applied analytically
  const float* Wq = (const float*)d_in[4];
  const float* Wk = (const float*)d_in[5];
  const float* Wv = (const float*)d_in[6];
  const float* Wo = (const float*)d_in[7];

  const size_t NE = (size_t)M_ROWS * D_MODEL;  // 4M elems
  const size_t NW = (size_t)D_MODEL * D_MODEL; // 1M elems
  __bf16* Xq  = (__bf16*)d_ws;
  __bf16* Xk  = Xq + NE;
  __bf16* Xv  = Xk + NE;
  __bf16* Wqb = Xv + NE;
  __bf16* Wkb = Wqb + NW;
  __bf16* Wvb = Wkb + NW;
  __bf16* Wob = Wvb + NW;
  __bf16* Q   = Wob + NW;
  __bf16* K   = Q + NE;
  __bf16* Vt  = K + NE;
  __bf16* A   = Xq;  // Xq consumed by proj_qkv before flash writes A

  CvtArgs ca;
  ca.src[0] = q_src; ca.dst[0] = Xq;  ca.n8[0] = (int)(NE / 8);
  ca.src[1] = k_src; ca.dst[1] = Xk;  ca.n8[1] = (int)(NE / 8);
  ca.src[2] = v_src; ca.dst[2] = Xv;  ca.n8[2] = (int)(NE / 8);
  ca.src[3] = Wq;    ca.dst[3] = Wqb; ca.n8[3] = (int)(NW / 8);  // x1/8
  ca.src[4] = Wk;    ca.dst[4] = Wkb; ca.n8[4] = (int)(NW / 8);
  ca.src[5] = Wv;    ca.dst[5] = Wvb; ca.n8[5] = (int)(NW / 8);
  ca.src[6] = Wo;    ca.dst[6] = Wob; ca.n8[6] = (int)(NW / 8);

  cvt_bf16<<<dim3((unsigned)(NE / 8 / 256), 1, 7), dim3(256), 0, stream>>>(ca);
  proj_qkv<<<dim3(4, 16, 3), dim3(512), 0, stream>>>(
      Xq, Xk, Xv, Wqb, Wkb, Wvb, Q, K, Vt);
  flash_attn<<<dim3(NT, BATCH * HEADS), dim3(512), 0, stream>>>(Q, K, Vt, A);
  proj_out<<<dim3(D_MODEL / 128, M_ROWS / 128), dim3(256), 0, stream>>>(
      A, Wob, (float*)d_out);
}

// Round 10
// 128.842 us; speedup vs baseline: 1.2016x; 1.1918x over previous
//
#include <hip/hip_runtime.h>
#include <hip/hip_bf16.h>

// MultiheadAttention: out = (softmax_causal((Xq Wq^T)(Xk Wk^T)^T / 8) (Xv Wv^T)) Wo^T
// B=2 S=2048 D=1024 H=16 dk=64. bf16 MFMA (16x16x32), fp32 accum.
// R10: flash = R7's dual-q-tile shared-KV structure widened to 8 waves/block
//      (waves 0-3 hi tile, 4-7 lo tile; one K/V stage serves both; no merge).
//      2x TLP vs R7, -26% serial steps. cvt/proj_qkv/proj_out unchanged.

typedef __attribute__((ext_vector_type(8))) __bf16 bf16x8;
typedef __attribute__((ext_vector_type(4))) __bf16 bf16x4;
typedef __attribute__((ext_vector_type(4))) float f32x4;

#define MFMA16(a, b, c) __builtin_amdgcn_mfma_f32_16x16x32_bf16((a), (b), (c), 0, 0, 0)

constexpr int D_MODEL = 1024;
constexpr int HEADS   = 16;
constexpr int DKH     = 64;
constexpr int BATCH   = 2;
constexpr int SEQ     = 2048;
constexpr int M_ROWS  = BATCH * SEQ;  // 4096
constexpr int QB = 64, KB = 64, NT = SEQ / QB;  // 32 q-tiles

typedef const unsigned int __attribute__((address_space(1)))* gas_u32;
typedef unsigned int __attribute__((address_space(3)))* las_u32;

// ---------------------------------------------------------------------------
// fp32 -> bf16 convert; seg 3 (Wq) pre-scaled by 1/8.
// Segs 0-5 granule-swizzled for the 8-phase GEMM staging (rule #21).
// ---------------------------------------------------------------------------
struct CvtArgs {
  const float* src[7];
  __bf16* dst[7];
  int n8[7];
};

__global__ __launch_bounds__(256) void cvt_bf16(CvtArgs a) {
  const int z = blockIdx.z;
  const int i = blockIdx.x * 256 + threadIdx.x;
  if (i >= a.n8[z]) return;
  const float sc = (z == 3) ? 0.125f : 1.0f;
  const float4* s = (const float4*)a.src[z] + (size_t)i * 2;
  float4 x = s[0], y = s[1];
  bf16x8 o = {(__bf16)(x.x * sc), (__bf16)(x.y * sc), (__bf16)(x.z * sc), (__bf16)(x.w * sc),
              (__bf16)(y.x * sc), (__bf16)(y.y * sc), (__bf16)(y.z * sc), (__bf16)(y.w * sc)};
  size_t oi = (size_t)i;
  if (z < 6) {
    const int row = i >> 7;  // 1024 elems = 128 granules per row
    oi = (size_t)((i & ~7) | ((i & 7) ^ (row & 7)));
  }
  *(bf16x8*)(a.dst[z] + oi * 8) = o;
}

// ---------------------------------------------------------------------------
// 8-phase 256x256 GEMM (unchanged from R7)
// ---------------------------------------------------------------------------
__global__ __launch_bounds__(512, 2) void proj_qkv(
    const __bf16* __restrict__ Xq, const __bf16* __restrict__ Xk,
    const __bf16* __restrict__ Xv, const __bf16* __restrict__ Wq,
    const __bf16* __restrict__ Wk, const __bf16* __restrict__ Wv,
    __bf16* __restrict__ Q, __bf16* __restrict__ K, __bf16* __restrict__ Vt) {
  __shared__ alignas(16) __bf16 As[2 * 256 * 64];  // 64 KB
  __shared__ alignas(16) __bf16 Bs[2 * 256 * 64];  // 64 KB

  int f = (blockIdx.z * gridDim.y + blockIdx.y) * gridDim.x + blockIdx.x;
  f = (f & 7) * 24 + (f >> 3);
  const int bx = f & 3, by = (f >> 2) & 15, bz = f >> 6;

  const __bf16* Ag; const __bf16* Bg;
  if (bz == 0)      { Ag = Xq; Bg = Wq; }
  else if (bz == 1) { Ag = Xk; Bg = Wk; }
  else              { Ag = Xv; Bg = Wv; }

  const int bm = by * 256, bn = bx * 256;
  const int tid = threadIdx.x, ln = tid & 63, wv = tid >> 6;
  const int wr = wv >> 2, wc = wv & 3;
  const int fr = ln & 15, fg = ln >> 4;

  auto stageA = [&](int buf, int h, int t) {
    const int kt = t * 64;
#pragma unroll
    for (int l = 0; l < 2; ++l) {
      const int gbase = l * 512 + wv * 64;
      const int d = gbase + ln;
      const __bf16* src = Ag + (size_t)(bm + h * 128 + (d >> 3)) * 1024 + kt + (d & 7) * 8;
      __builtin_amdgcn_global_load_lds((gas_u32)src,
          (las_u32)(As + (size_t)(buf * 2048 + h * 1024 + gbase) * 8), 16, 0, 0);
    }
  };
  auto stageB = [&](int buf, int h, int t) {
    const int kt = t * 64;
#pragma unroll
    for (int l = 0; l < 2; ++l) {
      const int gbase = l * 512 + wv * 64;
      const int d = gbase + ln;
      const __bf16* src = Bg + (size_t)(bn + h * 128 + (d >> 3)) * 1024 + kt + (d & 7) * 8;
      __builtin_amdgcn_global_load_lds((gas_u32)src,
          (las_u32)(Bs + (size_t)(buf * 2048 + h * 1024 + gbase) * 8), 16, 0, 0);
    }
  };

  f32x4 acc[8][4];
#pragma unroll
  for (int m = 0; m < 8; ++m)
#pragma unroll
    for (int n = 0; n < 4; ++n) acc[m][n] = (f32x4){0.f, 0.f, 0.f, 0.f};

  bf16x8 ra[4][2], rb[4][2];

  auto loadA = [&](int buf, int mbase) {
#pragma unroll
    for (int m = 0; m < 4; ++m)
#pragma unroll
      for (int kk = 0; kk < 2; ++kk) {
        const int row = wr * 128 + (mbase + m) * 16 + fr;
        ra[m][kk] = *(const bf16x8*)&As[(buf * 256 + row) * 64 +
                                        (((kk * 4 + fg) ^ (row & 7)) << 3)];
      }
  };
  auto loadB = [&](int buf, int n0) {
#pragma unroll
    for (int n = 0; n < 2; ++n)
#pragma unroll
      for (int kk = 0; kk < 2; ++kk) {
        const int row = wc * 64 + (n0 + n) * 16 + fr;
        rb[n0 + n][kk] = *(const bf16x8*)&Bs[(buf * 256 + row) * 64 +
                                             (((kk * 4 + fg) ^ (row & 7)) << 3)];
      }
  };
  auto quad = [&](int mb, int nb) {
    __builtin_amdgcn_s_setprio(1);
#pragma unroll
    for (int m = 0; m < 4; ++m)
#pragma unroll
      for (int n = 0; n < 2; ++n) {
        acc[mb + m][nb + n] = MFMA16(ra[m][0], rb[nb + n][0], acc[mb + m][nb + n]);
        acc[mb + m][nb + n] = MFMA16(ra[m][1], rb[nb + n][1], acc[mb + m][nb + n]);
      }
    __builtin_amdgcn_s_setprio(0);
  };

  stageB(0, 0, 0); stageB(0, 1, 0); stageA(0, 0, 0); stageA(0, 1, 0);
  stageB(1, 0, 1); stageA(1, 0, 1);
  asm volatile("s_waitcnt vmcnt(4)" ::: "memory");
  __builtin_amdgcn_s_barrier();

#pragma unroll 1
  for (int it = 0; it < 8; ++it) {
    const int T0 = 2 * it, T1 = 2 * it + 1;
    const bool nl = (it < 7);

    loadA(0, 0); loadB(0, 0);
    stageB(1, 1, T1);
    __builtin_amdgcn_s_barrier();
    quad(0, 0);
    __builtin_amdgcn_s_barrier();

    loadB(0, 2);
    stageA(1, 1, T1);
    __builtin_amdgcn_s_barrier();
    quad(0, 2);
    __builtin_amdgcn_s_barrier();

    loadA(0, 4);
    if (nl) stageB(0, 0, T0 + 2);
    __builtin_amdgcn_s_barrier();
    quad(4, 0);
    __builtin_amdgcn_s_barrier();

    if (nl) {
      stageB(0, 1, T0 + 2);
      asm volatile("s_waitcnt vmcnt(4)" ::: "memory");
    } else {
      asm volatile("s_waitcnt vmcnt(0)" ::: "memory");
    }
    __builtin_amdgcn_s_barrier();
    quad(4, 2);
    __builtin_amdgcn_s_barrier();

    loadA(1, 0); loadB(1, 0);
    if (nl) stageA(0, 0, T0 + 2);
    __builtin_amdgcn_s_barrier();
    quad(0, 0);
    __builtin_amdgcn_s_barrier();

    loadB(1, 2);
    if (nl) stageA(0, 1, T0 + 2);
    __builtin_amdgcn_s_barrier();
    quad(0, 2);
    __builtin_amdgcn_s_barrier();

    loadA(1, 4);
    if (nl) stageB(1, 0, T1 + 2);
    __builtin_amdgcn_s_barrier();
    quad(4, 0);
    __builtin_amdgcn_s_barrier();

    if (nl) {
      stageA(1, 0, T1 + 2);
      asm volatile("s_waitcnt vmcnt(4)" ::: "memory");
    }
    __builtin_amdgcn_s_barrier();
    quad(4, 2);
    __builtin_amdgcn_s_barrier();
  }

  if (bz == 2) {
    const int b = bm >> 11;
#pragma unroll
    for (int m = 0; m < 8; ++m)
#pragma unroll
      for (int n = 0; n < 4; ++n) {
        const int col = bn + wc * 64 + n * 16 + fr;
        const int s0  = (bm + wr * 128 + m * 16 + fg * 4) & (SEQ - 1);
        bf16x4 o = {(__bf16)acc[m][n][0], (__bf16)acc[m][n][1],
                    (__bf16)acc[m][n][2], (__bf16)acc[m][n][3]};
        *(bf16x4*)(Vt + (((size_t)(b * 1024 + col)) << 11) + s0) = o;
      }
  } else {
    __bf16* C = (bz == 0) ? Q : K;
#pragma unroll
    for (int m = 0; m < 8; ++m)
#pragma unroll
      for (int n = 0; n < 4; ++n)
#pragma unroll
        for (int r = 0; r < 4; ++r) {
          const int row = bm + wr * 128 + m * 16 + fg * 4 + r;
          const int col = bn + wc * 64 + n * 16 + fr;
          C[(size_t)row * 1024 + col] = (__bf16)acc[m][n][r];
        }
  }
}

// ---------------------------------------------------------------------------
// m97-style 128^2 GEMM (unchanged; A and Wo LINEAR layouts)
// ---------------------------------------------------------------------------
__global__ __launch_bounds__(256) void proj_out(const __bf16* __restrict__ Aattn,
                                                const __bf16* __restrict__ Wo,
                                                float* __restrict__ Out) {
  __shared__ alignas(16) __bf16 As[128 * 64];
  __shared__ alignas(16) __bf16 Bs[128 * 64];

  const int tid = threadIdx.x, ln = tid & 63, wv = tid >> 6;
  const int wr = wv >> 1, wc = wv & 1;
  const int fr = ln & 15, fg = ln >> 4;
  const int bm = blockIdx.y * 128, bn = blockIdx.x * 128;

  f32x4 acc[4][4];
#pragma unroll
  for (int m = 0; m < 4; ++m)
#pragma unroll
    for (int n = 0; n < 4; ++n) acc[m][n] = (f32x4){0.f, 0.f, 0.f, 0.f};

  for (int kt = 0; kt < 1024; kt += 64) {
    __syncthreads();
#pragma unroll
    for (int i = 0; i < 4; ++i) {
      const int c = wv * 4 + i;
      const int byte = c * 1024 + ln * 16;
      const int row = byte >> 7;
      const int col = (byte & 127) >> 1;
      const __bf16* ga = Aattn + (size_t)(bm + row) * 1024 + kt + col;
      const __bf16* gb = Wo + (size_t)(bn + row) * 1024 + kt + col;
      __builtin_amdgcn_global_load_lds((gas_u32)ga, (las_u32)(As + c * 512), 16, 0, 0);
      __builtin_amdgcn_global_load_lds((gas_u32)gb, (las_u32)(Bs + c * 512), 16, 0, 0);
    }
    __syncthreads();

#pragma unroll
    for (int kk = 0; kk < 2; ++kk) {
      const int kc = kk * 32 + fg * 8;
      bf16x8 af[4], bfv[4];
#pragma unroll
      for (int m = 0; m < 4; ++m)
        af[m] = *(const bf16x8*)&As[(wr * 64 + m * 16 + fr) * 64 + kc];
#pragma unroll
      for (int n = 0; n < 4; ++n)
        bfv[n] = *(const bf16x8*)&Bs[(wc * 64 + n * 16 + fr) * 64 + kc];
#pragma unroll
      for (int m = 0; m < 4; ++m)
#pragma unroll
        for (int n = 0; n < 4; ++n) acc[m][n] = MFMA16(af[m], bfv[n], acc[m][n]);
    }
  }

#pragma unroll
  for (int m = 0; m < 4; ++m)
#pragma unroll
    for (int n = 0; n < 4; ++n)
#pragma unroll
      for (int r = 0; r < 4; ++r) {
        const int row = bm + wr * 64 + m * 16 + fg * 4 + r;
        const int col = bn + wc * 64 + n * 16 + fr;
        Out[(size_t)row * 1024 + col] = acc[m][n][r];
      }
}

// ---------------------------------------------------------------------------
// Flash attention, causal. Block = paired q-tiles (hi = NT-1-j, lo = j),
// 8 waves: waves 0-3 own hi's 64 rows, waves 4-7 own lo's. One shared K/V
// stage per iter serves both groups (disjoint q-rows -> NO merge needed).
// Dbuf K/V, reg prefetch, defer-max THR=8, ones-MFMA row sums, setprio.
// ---------------------------------------------------------------------------
__device__ __forceinline__ int SWZ(int row, int col) {
  return row * 64 + (col ^ ((row & 7) << 3));
}

struct TileState {
  f32x4 acc[4];
  f32x4 l4;
  float m_r[4];
  bf16x8 q0, q1;
};

__global__ __launch_bounds__(512, 2) void flash_attn(
    const __bf16* __restrict__ Q, const __bf16* __restrict__ K,
    const __bf16* __restrict__ Vt, __bf16* __restrict__ O) {
  __shared__ alignas(16) __bf16 Ks[2][64 * 64];   // 16 KB (shared by all 8 waves)
  __shared__ alignas(16) __bf16 Vs[2][64 * 64];   // 16 KB
  __shared__ alignas(16) __bf16 Ps[8][16 * 64];   // 16 KB

  const int j  = blockIdx.x;            // lo tile; hi = NT-1-j (hi longest, first)
  const int hi = NT - 1 - j;
  const int b  = blockIdx.y >> 4;
  const int h  = blockIdx.y & 15;
  const int tid  = threadIdx.x;
  const int lane = tid & 63, wave = tid >> 6;
  const int grp = wave >> 2, w4 = wave & 3;   // grp 0 -> hi rows, 1 -> lo rows
  const int fr = lane & 15, fg = lane >> 4;
  const int sr = tid >> 3;              // staging row 0..63 (k for K, dk for V^T)
  const int sc = (tid & 7) * 8;         // staging granule

  const int myqt = grp ? j : hi;        // this wave-group's q-tile
  const __bf16* Kbase = K + (size_t)b * SEQ * D_MODEL + h * DKH;
  const __bf16* Vbase = Vt + (size_t)(blockIdx.y * DKH + sr) * SEQ;

  TileState S;
  {
    const size_t qrow = (size_t)(b * SEQ + myqt * QB + w4 * 16 + fr) * D_MODEL + h * DKH;
    S.q0 = *(const bf16x8*)(Q + qrow + fg * 8);
    S.q1 = *(const bf16x8*)(Q + qrow + 32 + fg * 8);
  }
#pragma unroll
  for (int n = 0; n < 4; ++n) S.acc[n] = (f32x4){0.f, 0.f, 0.f, 0.f};
  S.l4 = (f32x4){0.f, 0.f, 0.f, 0.f};
#pragma unroll
  for (int r = 0; r < 4; ++r) S.m_r[r] = -INFINITY;

  const bf16x8 ones = {(__bf16)1.f, (__bf16)1.f, (__bf16)1.f, (__bf16)1.f,
                       (__bf16)1.f, (__bf16)1.f, (__bf16)1.f, (__bf16)1.f};

  // prologue: stage tile 0 -> buf 0 (512 threads cover K + V in one pass)
  {
    const __bf16* kp = Kbase + (size_t)sr * D_MODEL + sc;
    bf16x8 k0 = *(const bf16x8*)kp;
    const __bf16* vp = Vbase + sc;
    bf16x8 v0 = *(const bf16x8*)vp;
    *(bf16x8*)&Ks[0][SWZ(sr, sc)] = k0;
    *(bf16x8*)&Vs[0][SWZ(sr, sc)] = v0;
  }
  __syncthreads();

  auto step = [&](const int t, const int cur, __bf16* __restrict__ ps) {
    f32x4 s[4];
    __builtin_amdgcn_s_setprio(1);
#pragma unroll
    for (int kb = 0; kb < 4; ++kb) {
      f32x4 a = (f32x4){0.f, 0.f, 0.f, 0.f};
      bf16x8 kf0 = *(const bf16x8*)&Ks[cur][SWZ(kb * 16 + fr, fg * 8)];
      bf16x8 kf1 = *(const bf16x8*)&Ks[cur][SWZ(kb * 16 + fr, 32 + fg * 8)];
      a = MFMA16(S.q0, kf0, a);
      a = MFMA16(S.q1, kf1, a);
      s[kb] = a;
    }
    __builtin_amdgcn_s_setprio(0);

    if (t == myqt) {  // causal mask: diagonal tile only
      const int q0r = myqt * QB + w4 * 16 + fg * 4;
      const int kc0 = t * KB + fr;
#pragma unroll
      for (int kb = 0; kb < 4; ++kb)
#pragma unroll
        for (int r = 0; r < 4; ++r)
          if (kc0 + kb * 16 > q0r + r) s[kb][r] = -INFINITY;
    }

    float tmax[4];
#pragma unroll
    for (int r = 0; r < 4; ++r)
      tmax[r] = fmaxf(fmaxf(s[0][r], s[1][r]), fmaxf(s[2][r], s[3][r]));

    bool need = false;
#pragma unroll
    for (int r = 0; r < 4; ++r) need |= (tmax[r] > S.m_r[r] + 8.f);
    if (__any(need)) {
#pragma unroll
      for (int off = 1; off < 16; off <<= 1)
#pragma unroll
        for (int r = 0; r < 4; ++r) tmax[r] = fmaxf(tmax[r], __shfl_xor(tmax[r], off));
      float corr[4];
#pragma unroll
      for (int r = 0; r < 4; ++r) {
        const float mn = fmaxf(S.m_r[r], tmax[r]);
        corr[r] = __expf(S.m_r[r] - mn);
        S.m_r[r] = mn;
      }
#pragma unroll
      for (int n = 0; n < 4; ++n)
#pragma unroll
        for (int r = 0; r < 4; ++r) S.acc[n][r] *= corr[r];
#pragma unroll
      for (int r = 0; r < 4; ++r) S.l4[r] *= corr[r];
    }

#pragma unroll
    for (int kb = 0; kb < 4; ++kb)
#pragma unroll
      for (int r = 0; r < 4; ++r) {
        const float p = __expf(s[kb][r] - S.m_r[r]);
        ps[SWZ(fg * 4 + r, kb * 16 + fr)] = (__bf16)p;
      }

    __builtin_amdgcn_s_setprio(1);
#pragma unroll
    for (int k2 = 0; k2 < 2; ++k2) {
      bf16x8 pf = *(const bf16x8*)&ps[SWZ(fr, k2 * 32 + fg * 8)];
#pragma unroll
      for (int n = 0; n < 4; ++n) {
        bf16x8 vf = *(const bf16x8*)&Vs[cur][SWZ(n * 16 + fr, k2 * 32 + fg * 8)];
        S.acc[n] = MFMA16(pf, vf, S.acc[n]);
      }
      S.l4 = MFMA16(pf, ones, S.l4);
    }
    __builtin_amdgcn_s_setprio(0);
  };

#pragma unroll 1
  for (int t = 0; t <= hi; ++t) {
    const int cur = t & 1;
    const bool pf = (t < hi);

    // issue next tile's global loads early (latency hides under compute)
    bf16x8 nk0, nv0;
    if (pf) {
      nk0 = *(const bf16x8*)(Kbase + (size_t)((t + 1) * KB + sr) * D_MODEL + sc);
      nv0 = *(const bf16x8*)(Vbase + (t + 1) * KB + sc);
    }

    if (t <= myqt) step(t, cur, &Ps[wave][0]);

    if (pf) {
      *(bf16x8*)&Ks[cur ^ 1][SWZ(sr, sc)] = nk0;
      *(bf16x8*)&Vs[cur ^ 1][SWZ(sr, sc)] = nv0;
    }
    __syncthreads();
  }

  // epilogue: O = acc / l  (each wave owns its rows; no merge)
  {
    const size_t obase = (size_t)(b * SEQ + myqt * QB + w4 * 16) * D_MODEL + h * DKH;
#pragma unroll
    for (int n = 0; n < 4; ++n)
#pragma unroll
      for (int r = 0; r < 4; ++r) {
        const int row = fg * 4 + r;
        O[obase + (size_t)row * D_MODEL + n * 16 + fr] =
            (__bf16)(S.acc[n][r] / S.l4[r]);
      }
  }
}

// ---------------------------------------------------------------------------
extern "C" void kernel_launch(void* const* d_in, const int* in_sizes, int n_in,
                              void* d_out, int out_size, void* d_ws, size_t ws_size,
                              hipStream_t stream) {
  const float* q_src = (const float*)d_in[0];
  const float* k_src = (const float*)d_in[1];
  const float* v_src = (const float*)d_in[2];
  // d_in[3] = causal tril mask (fixed) -> applied analytically
  const float* Wq = (const float*)d_in[4];
  const float* Wk = (const float*)d_in[5];
  const float* Wv = (const float*)d_in[6];
  const float* Wo = (const float*)d_in[7];

  const size_t NE = (size_t)M_ROWS * D_MODEL;  // 4M elems
  const size_t NW = (size_t)D_MODEL * D_MODEL; // 1M elems
  __bf16* Xq  = (__bf16*)d_ws;
  __bf16* Xk  = Xq + NE;
  __bf16* Xv  = Xk + NE;
  __bf16* Wqb = Xv + NE;
  __bf16* Wkb = Wqb + NW;
  __bf16* Wvb = Wkb + NW;
  __bf16* Wob = Wvb + NW;
  __bf16* Q   = Wob + NW;
  __bf16* K   = Q + NE;
  __bf16* Vt  = K + NE;
  __bf16* A   = Xq;  // Xq consumed by proj_qkv before flash writes A

  CvtArgs ca;
  ca.src[0] = q_src; ca.dst[0] = Xq;  ca.n8[0] = (int)(NE / 8);
  ca.src[1] = k_src; ca.dst[1] = Xk;  ca.n8[1] = (int)(NE / 8);
  ca.src[2] = v_src; ca.dst[2] = Xv;  ca.n8[2] = (int)(NE / 8);
  ca.src[3] = Wq;    ca.dst[3] = Wqb; ca.n8[3] = (int)(NW / 8);  // x1/8
  ca.src[4] = Wk;    ca.dst[4] = Wkb; ca.n8[4] = (int)(NW / 8);
  ca.src[5] = Wv;    ca.dst[5] = Wvb; ca.n8[5] = (int)(NW / 8);
  ca.src[6] = Wo;    ca.dst[6] = Wob; ca.n8[6] = (int)(NW / 8);

  cvt_bf16<<<dim3((unsigned)(NE / 8 / 256), 1, 7), dim3(256), 0, stream>>>(ca);
  proj_qkv<<<dim3(4, 16, 3), dim3(512), 0, stream>>>(
      Xq, Xk, Xv, Wqb, Wkb, Wvb, Q, K, Vt);
  flash_attn<<<dim3(NT / 2, BATCH * HEADS), dim3(512), 0, stream>>>(Q, K, Vt, A);
  proj_out<<<dim3(D_MODEL / 128, M_ROWS / 128), dim3(256), 0, stream>>>(
      A, Wob, (float*)d_out);
}